// Round 7
// baseline (324.641 us; speedup 1.0000x reference)
//
#include <hip/hip_runtime.h>
#include <cstdint>
#include <cstddef>

#define NNODES 50000
#define NEDGES 800000
#define INDIM  256
#define HD     128   // H*D
#define NH     4
#define NEG    0.2f

#define SCAN_B ((NNODES + 255) / 256)   // 196 blocks

typedef __attribute__((ext_vector_type(8))) short   short8;   // 8 bf16 (4 VGPRs)
typedef __attribute__((ext_vector_type(8))) ushort  ushort8;
typedef __attribute__((ext_vector_type(4))) float   floatx4;

// f32 -> bf16 (round-to-nearest-even), raw bits
__device__ __forceinline__ ushort f2bf(float f) {
    unsigned u = __float_as_uint(f);
    unsigned r = u + 0x7fffu + ((u >> 16) & 1u);
    return (ushort)(r >> 16);
}
__device__ __forceinline__ float bf2f(ushort u) {
    return __uint_as_float(((unsigned)u) << 16);
}

// ================= W convert+transpose (LDS-tiled): Wt[n][k] bf16 =================
__global__ __launch_bounds__(256) void conv_w_kernel(
        const float* __restrict__ Wsrc, const float* __restrict__ Wdst,
        ushort* __restrict__ Wt) {
    __shared__ float t[32][33];
    int kb = blockIdx.x * 32, nb = blockIdx.y * 32;
    for (int i = threadIdx.y; i < 32; i += 8) {
        int k = kb + i, n = nb + threadIdx.x;
        float v = (n < HD) ? Wsrc[(size_t)k * HD + n] : Wdst[(size_t)k * HD + (n - HD)];
        t[i][threadIdx.x] = v;
    }
    __syncthreads();
    for (int i = threadIdx.y; i < 32; i += 8) {
        int n = nb + i, k = kb + threadIdx.x;
        Wt[(size_t)n * INDIM + k] = f2bf(t[threadIdx.x][i]);
    }
}

// LDS chunk swizzle: conflict-free staging writes + fragment reads
__device__ __forceinline__ int swz(int c) { return c ^ ((c >> 4) & 7); }

// ================= MFMA GEMM (merged cols) =================
// One block = 64 rows x 256 cols (el cols 0-127, er cols 128-255).
// 4 waves; wave w = rows w*16..w*16+15 (1 m-tile) x 16 n-tiles.
// h read as f32 with inline f2bf during staging (staged once, used by all 256 cols).
__global__ __launch_bounds__(256) void gemm_mfma_kernel(
        const float* __restrict__ h, const ushort* __restrict__ Wt,
        const float* __restrict__ bsrc, const float* __restrict__ bdst,
        ushort* __restrict__ el_bf, float* __restrict__ er) {
    __shared__ ushort As[256 * 8];    // 256 fragment-chunks (64 rows x 32 k)
    __shared__ ushort Bs[1024 * 8];   // 1024 chunks (256 n x 32 k)

    const int tid  = threadIdx.x;
    const int wave = tid >> 6, lane = tid & 63;
    const int row0 = blockIdx.x * 64;
    const int l15  = lane & 15, quad = lane >> 4;

    floatx4 acc[16];
#pragma unroll
    for (int j = 0; j < 16; ++j) acc[j] = (floatx4){0.f, 0.f, 0.f, 0.f};

    for (int kk = 0; kk < INDIM; kk += 32) {
        // ---- stage A: 256 chunks, 1/thread; f32 -> bf16 inline ----
        {
            int r = tid >> 2, kq = tid & 3;
            int c = (r >> 4) * 64 + kq * 16 + (r & 15);
            int grow = row0 + r;
            ushort8 aw = (ushort8){0,0,0,0,0,0,0,0};
            if (grow < NNODES) {
                const float* hp = h + (size_t)grow * INDIM + kk + kq * 8;
                float4 v0 = *(const float4*)(hp);
                float4 v1 = *(const float4*)(hp + 4);
                aw[0] = f2bf(v0.x); aw[1] = f2bf(v0.y); aw[2] = f2bf(v0.z); aw[3] = f2bf(v0.w);
                aw[4] = f2bf(v1.x); aw[5] = f2bf(v1.y); aw[6] = f2bf(v1.z); aw[7] = f2bf(v1.w);
            }
            *(ushort8*)(As + swz(c) * 8) = aw;
        }
        // ---- stage B: 1024 chunks, 4/thread ----
#pragma unroll
        for (int it = 0; it < 4; ++it) {
            int idx = tid + it * 256;
            int rn = idx >> 2, kq = idx & 3;
            int c = (rn >> 4) * 64 + kq * 16 + (rn & 15);
            ushort8 bw = *(const ushort8*)(Wt + (size_t)rn * INDIM + kk + kq * 8);
            *(ushort8*)(Bs + swz(c) * 8) = bw;
        }
        __syncthreads();

        short8 af = *(const short8*)(As + swz(wave * 64 + quad * 16 + l15) * 8);
#pragma unroll
        for (int tn = 0; tn < 16; ++tn) {
            short8 bf = *(const short8*)(Bs + swz(tn * 64 + quad * 16 + l15) * 8);
            acc[tn] = __builtin_amdgcn_mfma_f32_16x16x32_bf16(af, bf, acc[tn], 0, 0, 0);
        }
        __syncthreads();
    }

    // epilogue: C/D layout col=lane&15, row=quad*4+reg
#pragma unroll
    for (int tn = 0; tn < 16; ++tn) {
        int col = tn * 16 + l15;
        if (col < HD) {
            float bias = bsrc[col];
#pragma unroll
            for (int reg = 0; reg < 4; ++reg) {
                int row = row0 + wave * 16 + quad * 4 + reg;
                if (row < NNODES)
                    el_bf[(size_t)row * HD + col] = f2bf(acc[tn][reg] + bias);
            }
        } else {
            float bias = bdst[col - HD];
#pragma unroll
            for (int reg = 0; reg < 4; ++reg) {
                int row = row0 + wave * 16 + quad * 4 + reg;
                if (row < NNODES)
                    er[(size_t)row * HD + (col - HD)] = acc[tn][reg] + bias;
            }
        }
    }
}

// ================= CSR build =================
__global__ __launch_bounds__(256) void hist_kernel(
        const int* __restrict__ dst, int* __restrict__ cnt_work) {
    int e = blockIdx.x * blockDim.x + threadIdx.x;
    if (e < NEDGES) atomicAdd(cnt_work + dst[e], 1);
}

// ---- 3-phase multi-block scan ----
__global__ __launch_bounds__(256) void scan_partial_kernel(
        const int* __restrict__ cnt, int* __restrict__ partials) {
    __shared__ int lds[256];
    int i = blockIdx.x * 256 + threadIdx.x;
    lds[threadIdx.x] = (i < NNODES) ? cnt[i] : 0;
    __syncthreads();
    for (int off = 128; off > 0; off >>= 1) {
        if (threadIdx.x < off) lds[threadIdx.x] += lds[threadIdx.x + off];
        __syncthreads();
    }
    if (threadIdx.x == 0) partials[blockIdx.x] = lds[0];
}

__global__ __launch_bounds__(256) void scan_offsets_kernel(
        int* __restrict__ partials, int* __restrict__ rowptr) {
    __shared__ int lds[256];
    int t = threadIdx.x;
    int v = (t < SCAN_B) ? partials[t] : 0;
    lds[t] = v;
    __syncthreads();
    for (int off = 1; off < 256; off <<= 1) {
        int u = (t >= off) ? lds[t - off] : 0;
        __syncthreads();
        lds[t] += u;
        __syncthreads();
    }
    if (t < SCAN_B) partials[t] = lds[t] - v;      // exclusive
    if (t == 255) rowptr[NNODES] = lds[255];       // total
}

__global__ __launch_bounds__(256) void scan_final_kernel(
        int* __restrict__ cnt_work, const int* __restrict__ partials,
        int* __restrict__ rowptr) {
    __shared__ int lds[256];
    int i = blockIdx.x * 256 + threadIdx.x;
    int t = threadIdx.x;
    int v = (i < NNODES) ? cnt_work[i] : 0;
    lds[t] = v;
    __syncthreads();
    for (int off = 1; off < 256; off <<= 1) {
        int u = (t >= off) ? lds[t - off] : 0;
        __syncthreads();
        lds[t] += u;
        __syncthreads();
    }
    if (i < NNODES) {
        int start = partials[blockIdx.x] + lds[t] - v;
        rowptr[i] = start;
        cnt_work[i] = start;
    }
}

// scatter (eidx, esrc) as one int2 per slot
__global__ __launch_bounds__(256) void scatter_kernel(
        const int* __restrict__ src, const int* __restrict__ dst,
        int* __restrict__ cnt_work, int2* __restrict__ epair) {
    int e = blockIdx.x * blockDim.x + threadIdx.x;
    if (e >= NEDGES) return;
    int s = src[e];
    int pos = atomicAdd(cnt_work + dst[e], 1);
    epair[pos] = make_int2(e, s);
}

// ================= fused: scores + online softmax + aggregate + normalize =================
// one wave per node; lane l owns dims 2l,2l+1; head hh = l>>4.
#define DEGCAP 128

__global__ __launch_bounds__(256) void node_fused_kernel(
        const ushort* __restrict__ el_bf, const float* __restrict__ er,
        const int* __restrict__ rowptr, const int2* __restrict__ epair,
        const float* __restrict__ attn,
        float* __restrict__ out_feat, float* __restrict__ out_a) {
    __shared__ float sp[4][DEGCAP * NH];   // 2 KB per wave

    const int wv = threadIdx.x >> 6;
    const int n = blockIdx.x * 4 + wv;
    if (n >= NNODES) return;
    const int lane = threadIdx.x & 63;
    const int hh = lane >> 4;
    const int lo = rowptr[n], hi = rowptr[n + 1];
    const int deg = hi - lo;
    float* spw = sp[wv];

    const float2 rv = *(const float2*)(er + (size_t)n * HD + lane * 2);
    const float a0 = attn[lane * 2], a1 = attn[lane * 2 + 1];

    float m = -3.4e38f, lsum = 0.0f, acc0 = 0.0f, acc1 = 0.0f;

#define LOADU(var, j) \
    if ((j) < deg) { int s_ = epair[lo + (j)].y; \
        var = *(const ushort2*)(el_bf + (size_t)s_ * HD + lane * 2); }

#define PROC(u, j) \
    if ((j) < deg) { \
        float evx = bf2f(u.x), evy = bf2f(u.y); \
        if ((j) + 4 < deg) { int s_ = epair[lo + (j) + 4].y; \
            u = *(const ushort2*)(el_bf + (size_t)s_ * HD + lane * 2); } \
        float x0 = evx + rv.x; x0 = x0 > 0.f ? x0 : NEG * x0; \
        float x1 = evy + rv.y; x1 = x1 > 0.f ? x1 : NEG * x1; \
        float p = x0 * a0 + x1 * a1; \
        p += __shfl_xor(p, 1, 16); \
        p += __shfl_xor(p, 2, 16); \
        p += __shfl_xor(p, 4, 16); \
        p += __shfl_xor(p, 8, 16); \
        if ((lane & 15) == 0) spw[(j) * NH + hh] = p; \
        float d_ = p - m; \
        bool up_ = (d_ >= 0.f); \
        float e_ = __expf(up_ ? -d_ : d_);   /* exp(-|d|), single transcendental */ \
        float sc = up_ ? e_ : 1.f; \
        float w  = up_ ? 1.f : e_; \
        if (up_) m = p; \
        lsum = lsum * sc + w; \
        acc0 = acc0 * sc + w * evx; \
        acc1 = acc1 * sc + w * evy; \
    }

    if (deg > 0 && deg <= DEGCAP) {
        ushort2 u0 = {0,0}, u1 = {0,0}, u2 = {0,0}, u3 = {0,0};
        LOADU(u0, 0) LOADU(u1, 1) LOADU(u2, 2) LOADU(u3, 3)
        for (int j0 = 0; j0 < deg; j0 += 4) {
            PROC(u0, j0)
            PROC(u1, j0 + 1)
            PROC(u2, j0 + 2)
            PROC(u3, j0 + 3)
        }
    } else if (deg > DEGCAP) {
        // fallback pass 1: online softmax only (no score stash)
        ushort2 u = {0,0};
        { int s_ = epair[lo].y; u = *(const ushort2*)(el_bf + (size_t)s_ * HD + lane * 2); }
        for (int i = lo; i < hi; ++i) {
            float evx = bf2f(u.x), evy = bf2f(u.y);
            if (i + 1 < hi) { int s_ = epair[i + 1].y;
                u = *(const ushort2*)(el_bf + (size_t)s_ * HD + lane * 2); }
            float x0 = evx + rv.x; x0 = x0 > 0.f ? x0 : NEG * x0;
            float x1 = evy + rv.y; x1 = x1 > 0.f ? x1 : NEG * x1;
            float p = x0 * a0 + x1 * a1;
            p += __shfl_xor(p, 1, 16);
            p += __shfl_xor(p, 2, 16);
            p += __shfl_xor(p, 4, 16);
            p += __shfl_xor(p, 8, 16);
            float mn = fmaxf(m, p);
            float sc = __expf(m - mn);
            float w  = __expf(p - mn);
            lsum = lsum * sc + w;
            acc0 = acc0 * sc + w * evx;
            acc1 = acc1 * sc + w * evy;
            m = mn;
        }
    }

    // write aggregated features
    float2 o;
    if (deg == 0) { o.x = 0.0f; o.y = 0.0f; }
    else { float inv = 1.0f / lsum; o.x = acc0 * inv; o.y = acc1 * inv; }
    *(float2*)(out_feat + (size_t)n * HD + lane * 2) = o;

    if (deg == 0) return;

    // normalize + write attention weights
    float inv = 1.0f / lsum;
    if (deg <= DEGCAP) {
        float mh   = __shfl(m,   (lane & 3) << 4, 64);
        float invh = __shfl(inv, (lane & 3) << 4, 64);
        for (int j = (lane >> 2); j < deg; j += 16) {
            int e = epair[lo + j].x;
            float p = spw[j * NH + (lane & 3)];
            out_a[(size_t)e * NH + (lane & 3)] = __expf(p - mh) * invh;
        }
    } else {
        // fallback pass 2: recompute scores and write a
        for (int i = lo; i < hi; ++i) {
            int s_ = epair[i].y;
            ushort2 u = *(const ushort2*)(el_bf + (size_t)s_ * HD + lane * 2);
            float evx = bf2f(u.x), evy = bf2f(u.y);
            float x0 = evx + rv.x; x0 = x0 > 0.f ? x0 : NEG * x0;
            float x1 = evy + rv.y; x1 = x1 > 0.f ? x1 : NEG * x1;
            float p = x0 * a0 + x1 * a1;
            p += __shfl_xor(p, 1, 16);
            p += __shfl_xor(p, 2, 16);
            p += __shfl_xor(p, 4, 16);
            p += __shfl_xor(p, 8, 16);
            if ((lane & 15) == 0) {
                int e = epair[i].x;
                out_a[(size_t)e * NH + hh] = __expf(p - m) * inv;
            }
        }
    }
#undef LOADU
#undef PROC
}

extern "C" void kernel_launch(void* const* d_in, const int* in_sizes, int n_in,
                              void* d_out, int out_size, void* d_ws, size_t ws_size,
                              hipStream_t stream) {
    const float* h    = (const float*)d_in[0];
    const int*   src  = (const int*)d_in[1];
    const int*   dst  = (const int*)d_in[2];
    const float* Wsrc = (const float*)d_in[3];
    const float* bsrc = (const float*)d_in[4];
    const float* Wdst = (const float*)d_in[5];
    const float* bdst = (const float*)d_in[6];
    const float* attn = (const float*)d_in[7];

    float* out_feat = (float*)d_out;                       // N*128
    float* out_a    = out_feat + (size_t)NNODES * HD;      // E*4

    // workspace layout (all segments 8B+ aligned)
    float*  er       = (float*)d_ws;                         // N*128 f32 (25.6 MB)
    ushort* Wt       = (ushort*)(er + (size_t)NNODES * HD);  // 256*256 bf16 (128 KB)
    ushort* el_bf    = Wt + 2 * HD * INDIM;                  // N*128 bf16 (12.8 MB)
    int2*   epair    = (int2*)(el_bf + (size_t)NNODES * HD); // E int2 (6.4 MB)
    int*    cnt_work = (int*)(epair + NEDGES);               // N
    int*    rowptr   = cnt_work + NNODES;                    // N+1
    int*    partials = rowptr + NNODES + 1;                  // SCAN_B

    hipMemsetAsync(cnt_work, 0, NNODES * sizeof(int), stream);

    dim3 cwgrid(INDIM / 32, 256 / 32);
    conv_w_kernel<<<cwgrid, dim3(32, 8), 0, stream>>>(Wsrc, Wdst, Wt);

    gemm_mfma_kernel<<<(NNODES + 63) / 64, 256, 0, stream>>>(h, Wt, bsrc, bdst, el_bf, er);

    hist_kernel<<<(NEDGES + 255) / 256, 256, 0, stream>>>(dst, cnt_work);
    scan_partial_kernel<<<SCAN_B, 256, 0, stream>>>(cnt_work, partials);
    scan_offsets_kernel<<<1, 256, 0, stream>>>(partials, rowptr);
    scan_final_kernel<<<SCAN_B, 256, 0, stream>>>(cnt_work, partials, rowptr);
    scatter_kernel<<<(NEDGES + 255) / 256, 256, 0, stream>>>(src, dst, cnt_work, epair);

    node_fused_kernel<<<(NNODES + 3) / 4, 256, 0, stream>>>(
        el_bf, er, rowptr, epair, attn, out_feat, out_a);
}